// Round 1
// baseline (276.956 us; speedup 1.0000x reference)
//
#include <hip/hip_runtime.h>

// relative_depth_crit: gather z_A, z_B from depth, compute ranking/metric loss,
// mean over 64*100000 points. Memory-bound: 128 MB index streams + ~84 MB depth
// (gathered; fits in L3). Roofline ~34 us at 6.3 TB/s.

constexpr int B = 64;
constexpr int H = 512;
constexpr int W = 640;
constexpr int P = 100000;           // divisible by 4
constexpr int N4 = (B * P) / 4;     // 1,600,000 int4 work items
constexpr float INV_N = 1.0f / (float)(B * P);
constexpr float MARGIN = 1.0f;

__device__ __forceinline__ float loss_elem(const float* __restrict__ d,
                                           int ya, int xa, int yb, int xb, int od) {
    float za = d[ya * W + xa];
    float zb = d[yb * W + xb];
    float zd = za - zb;
    float gt = (float)(od - 1);          // {-1, 0, 1}
    float mask = fabsf(gt);              // {0, 1}
    float t = fminf(gt * zd, MARGIN);
    float l_rank = __logf(1.0f + __expf(-t));
    float l_eq = fmaxf(zd * zd, MARGIN * MARGIN);
    return mask * l_rank + (1.0f - mask) * l_eq;
}

__global__ __launch_bounds__(256) void rdc_kernel(
        const float* __restrict__ depth,
        const int4* __restrict__ xA, const int4* __restrict__ yA,
        const int4* __restrict__ xB, const int4* __restrict__ yB,
        const int4* __restrict__ ord,
        float* __restrict__ out) {
    int i = blockIdx.x * blockDim.x + threadIdx.x;
    float acc = 0.0f;
    if (i < N4) {
        // 4 consecutive points; all share batch b since P % 4 == 0
        int b = i / (P / 4);
        const float* d = depth + (size_t)b * (H * W);
        int4 xa = xA[i], ya = yA[i], xb = xB[i], yb = yB[i], od = ord[i];
        acc += loss_elem(d, ya.x, xa.x, yb.x, xb.x, od.x);
        acc += loss_elem(d, ya.y, xa.y, yb.y, xb.y, od.y);
        acc += loss_elem(d, ya.z, xa.z, yb.z, xb.z, od.z);
        acc += loss_elem(d, ya.w, xa.w, yb.w, xb.w, od.w);
    }

    // wave-64 reduction
    #pragma unroll
    for (int off = 32; off > 0; off >>= 1)
        acc += __shfl_down(acc, off, 64);

    __shared__ float wsum[4];            // 256 threads = 4 waves
    int lane = threadIdx.x & 63;
    int wid  = threadIdx.x >> 6;
    if (lane == 0) wsum[wid] = acc;
    __syncthreads();
    if (wid == 0) {
        float v = (lane < 4) ? wsum[lane] : 0.0f;
        #pragma unroll
        for (int off = 2; off > 0; off >>= 1)
            v += __shfl_down(v, off, 64);
        if (lane == 0)
            atomicAdd(out, v * INV_N);
    }
}

extern "C" void kernel_launch(void* const* d_in, const int* in_sizes, int n_in,
                              void* d_out, int out_size, void* d_ws, size_t ws_size,
                              hipStream_t stream) {
    const float* depth = (const float*)d_in[0];
    const int4* xA = (const int4*)d_in[1];
    const int4* yA = (const int4*)d_in[2];
    const int4* xB = (const int4*)d_in[3];
    const int4* yB = (const int4*)d_in[4];
    const int4* ord = (const int4*)d_in[5];
    float* out = (float*)d_out;

    hipMemsetAsync(out, 0, sizeof(float), stream);

    int blocks = (N4 + 255) / 256;       // 6250
    rdc_kernel<<<blocks, 256, 0, stream>>>(depth, xA, yA, xB, yB, ord, out);
}

// Round 2
// 243.657 us; speedup vs baseline: 1.1367x; 1.1367x over previous
//
#include <hip/hip_runtime.h>

// relative_depth_crit — R1: XCD-aware batch swizzle + nontemporal index loads
// + workspace partial sums (no atomic contention, no memset).
//
// Traffic model: 128 MB index streams (read once, nt) + 84 MB depth (gathered,
// each batch slab pinned to ONE XCD's L2 via swizzle). Ideal ~212 MB HBM.

constexpr int B = 64;
constexpr int H = 512;
constexpr int W = 640;
constexpr int P = 100000;              // divisible by 4
constexpr int N4B = P / 4;             // 25000 vec4 items per batch
constexpr int CHUNKS = (N4B + 255) / 256;   // 98 blocks per batch
constexpr int NBLK = B * CHUNKS;       // 6272 blocks total (64 = 8 XCD groups * 8)
constexpr float INV_N = 1.0f / (float)(B * P);
constexpr float MARGIN = 1.0f;

typedef int vint4 __attribute__((ext_vector_type(4)));

__device__ __forceinline__ float loss_elem(const float* __restrict__ d,
                                           int ya, int xa, int yb, int xb, int od) {
    float za = d[ya * W + xa];
    float zb = d[yb * W + xb];
    float zd = za - zb;
    float gt = (float)(od - 1);          // {-1, 0, 1}
    float mask = fabsf(gt);              // {0, 1}
    float t = fminf(gt * zd, MARGIN);
    float l_rank = __logf(1.0f + __expf(-t));
    float l_eq = fmaxf(zd * zd, MARGIN * MARGIN);
    return mask * l_rank + (1.0f - mask) * l_eq;
}

__global__ __launch_bounds__(256) void rdc_kernel(
        const float* __restrict__ depth,
        const vint4* __restrict__ xA, const vint4* __restrict__ yA,
        const vint4* __restrict__ xB, const vint4* __restrict__ yB,
        const vint4* __restrict__ ord,
        float* __restrict__ partials) {
    int j = blockIdx.x;
    // XCD-aware swizzle: blocks are dispatched round-robin over 8 XCDs, so
    // j%8 ~ XCD id. Keep each XCD on batches b == j%8 (mod 8), 98 consecutive
    // block-groups per batch -> one 1.31 MB slab resident per XCD L2 at a time.
    int x = j & 7;                 // XCD slot
    int g = j >> 3;                // group 0..783
    int b = ((g / CHUNKS) << 3) + x;   // batch 0..63
    int c = g % CHUNKS;            // chunk within batch 0..97
    int e = c * 256 + threadIdx.x; // vec4 element within batch

    float acc = 0.0f;
    if (e < N4B) {
        int i = b * N4B + e;
        const float* d = depth + (size_t)b * (H * W);
        // index streams: read exactly once -> nontemporal (don't pollute L2)
        vint4 xa = __builtin_nontemporal_load(&xA[i]);
        vint4 ya = __builtin_nontemporal_load(&yA[i]);
        vint4 xb = __builtin_nontemporal_load(&xB[i]);
        vint4 yb = __builtin_nontemporal_load(&yB[i]);
        vint4 od = __builtin_nontemporal_load(&ord[i]);
        acc += loss_elem(d, ya.x, xa.x, yb.x, xb.x, od.x);
        acc += loss_elem(d, ya.y, xa.y, yb.y, xb.y, od.y);
        acc += loss_elem(d, ya.z, xa.z, yb.z, xb.z, od.z);
        acc += loss_elem(d, ya.w, xa.w, yb.w, xb.w, od.w);
    }

    // wave-64 reduction
    #pragma unroll
    for (int off = 32; off > 0; off >>= 1)
        acc += __shfl_down(acc, off, 64);

    __shared__ float wsum[4];
    int lane = threadIdx.x & 63;
    int wid  = threadIdx.x >> 6;
    if (lane == 0) wsum[wid] = acc;
    __syncthreads();
    if (wid == 0 && lane == 0) {
        partials[j] = wsum[0] + wsum[1] + wsum[2] + wsum[3];
    }
}

__global__ __launch_bounds__(256) void rdc_finalize(
        const float* __restrict__ partials, float* __restrict__ out, int n) {
    float acc = 0.0f;
    for (int k = threadIdx.x; k < n; k += 256)
        acc += partials[k];
    #pragma unroll
    for (int off = 32; off > 0; off >>= 1)
        acc += __shfl_down(acc, off, 64);
    __shared__ float wsum[4];
    int lane = threadIdx.x & 63;
    int wid  = threadIdx.x >> 6;
    if (lane == 0) wsum[wid] = acc;
    __syncthreads();
    if (wid == 0 && lane == 0)
        out[0] = (wsum[0] + wsum[1] + wsum[2] + wsum[3]) * INV_N;
}

// Fallback (ws too small): original atomic version
__global__ __launch_bounds__(256) void rdc_kernel_atomic(
        const float* __restrict__ depth,
        const vint4* __restrict__ xA, const vint4* __restrict__ yA,
        const vint4* __restrict__ xB, const vint4* __restrict__ yB,
        const vint4* __restrict__ ord,
        float* __restrict__ out) {
    int j = blockIdx.x;
    int x = j & 7, g = j >> 3;
    int b = ((g / CHUNKS) << 3) + x;
    int c = g % CHUNKS;
    int e = c * 256 + threadIdx.x;
    float acc = 0.0f;
    if (e < N4B) {
        int i = b * N4B + e;
        const float* d = depth + (size_t)b * (H * W);
        vint4 xa = __builtin_nontemporal_load(&xA[i]);
        vint4 ya = __builtin_nontemporal_load(&yA[i]);
        vint4 xb = __builtin_nontemporal_load(&xB[i]);
        vint4 yb = __builtin_nontemporal_load(&yB[i]);
        vint4 od = __builtin_nontemporal_load(&ord[i]);
        acc += loss_elem(d, ya.x, xa.x, yb.x, xb.x, od.x);
        acc += loss_elem(d, ya.y, xa.y, yb.y, xb.y, od.y);
        acc += loss_elem(d, ya.z, xa.z, yb.z, xb.z, od.z);
        acc += loss_elem(d, ya.w, xa.w, yb.w, xb.w, od.w);
    }
    #pragma unroll
    for (int off = 32; off > 0; off >>= 1)
        acc += __shfl_down(acc, off, 64);
    __shared__ float wsum[4];
    int lane = threadIdx.x & 63;
    int wid  = threadIdx.x >> 6;
    if (lane == 0) wsum[wid] = acc;
    __syncthreads();
    if (wid == 0 && lane == 0)
        atomicAdd(out, (wsum[0] + wsum[1] + wsum[2] + wsum[3]) * INV_N);
}

extern "C" void kernel_launch(void* const* d_in, const int* in_sizes, int n_in,
                              void* d_out, int out_size, void* d_ws, size_t ws_size,
                              hipStream_t stream) {
    const float* depth = (const float*)d_in[0];
    const vint4* xA = (const vint4*)d_in[1];
    const vint4* yA = (const vint4*)d_in[2];
    const vint4* xB = (const vint4*)d_in[3];
    const vint4* yB = (const vint4*)d_in[4];
    const vint4* ord = (const vint4*)d_in[5];
    float* out = (float*)d_out;

    if (ws_size >= NBLK * sizeof(float)) {
        float* partials = (float*)d_ws;
        rdc_kernel<<<NBLK, 256, 0, stream>>>(depth, xA, yA, xB, yB, ord, partials);
        rdc_finalize<<<1, 256, 0, stream>>>(partials, out, NBLK);
    } else {
        hipMemsetAsync(out, 0, sizeof(float), stream);
        rdc_kernel_atomic<<<NBLK, 256, 0, stream>>>(depth, xA, yA, xB, yB, ord, out);
    }
}